// Round 4
// baseline (231.943 us; speedup 1.0000x reference)
//
#include <hip/hip_runtime.h>
#include <hip/hip_cooperative_groups.h>
#include <hip/hip_bf16.h>
#include <math.h>

namespace cg = cooperative_groups;

// Problem constants
#define BB 8
#define SS 2048
#define DD 256
#define FF 8
#define NTOK (BB*SS)   // 16384

#define BM 32
#define NGRP (NTOK/BM) // 512

typedef __bf16 bf16x8 __attribute__((ext_vector_type(8)));
typedef float  f32x4  __attribute__((ext_vector_type(4)));
typedef float  f32x2  __attribute__((ext_vector_type(2)));

__device__ __forceinline__ unsigned pack2_bf16(float a, float b) {
    return (__float_as_uint(a) >> 16) | (__float_as_uint(b) & 0xFFFF0000u);
}
__device__ __forceinline__ float fast_tanh(float x) {
    float e = __expf(2.0f * x);
    return 1.0f - 2.0f * __builtin_amdgcn_rcpf(e + 1.0f);
}
__device__ __forceinline__ unsigned char f32_to_fp8(float v) {
    return (unsigned char)(__builtin_amdgcn_cvt_pk_fp8_f32(v, v, 0, false) & 0xFF);
}

// ---------------- R11: single cooperative mega-kernel ----------------
// Model from R4/R8/R10 deltas: dur_us ~= 44us fill + ~8.5us per dispatch + kernel times.
// Kernels are near their traffic floors (A ~7us, B ~4us); 3 dispatches cost ~26us of
// overhead. Fuse W1->bf16 convert, GEMM+tanh->fp8 table, and gather+score into ONE
// dispatch with two grid.sync()s. Phases A/B are the R10-verified bodies unchanged.
// grid 512 x 512thr; launch_bounds(512,4) caps VGPR at 128 -> 2 blocks/CU co-resident
// (LDS 16.5KB x 2 fits); all phases grid-stride so a clamped grid stays correct.
__global__ __launch_bounds__(512, 4) void mega_kernel(
    const float* __restrict__ x, const float* __restrict__ W1,
    const float* __restrict__ b1,
    const int* __restrict__ select_idx, const int* __restrict__ word_mask,
    const float* __restrict__ w2, const float* __restrict__ b2,
    unsigned char* __restrict__ table, unsigned short* __restrict__ W1b,
    float* __restrict__ out)
{
    // 32 x 256 bf16 x-tile = 16 KB; reused as fp8 scratch [32][272] in the epilogue
    __shared__ __align__(16) unsigned short xs[BM * DD];

    cg::grid_group grid = cg::this_grid();
    const int tid = threadIdx.x;
    const int bx  = blockIdx.x;
    const int nb  = gridDim.x;

    // ---- phase W: W1 f32 -> bf16 (128 KB) + zero table padding row 0 ----
    {
        int gt = bx * 512 + tid;
        for (int i = gt; i < (DD * DD / 8); i += nb * 512) {   // 8192 chunks of 8 floats
            f32x4 a = *(const f32x4*)&W1[(size_t)i * 8];
            f32x4 b = *(const f32x4*)&W1[(size_t)i * 8 + 4];
            uint4 p;
            p.x = pack2_bf16(a.x, a.y); p.y = pack2_bf16(a.z, a.w);
            p.z = pack2_bf16(b.x, b.y); p.w = pack2_bf16(b.z, b.w);
            *(uint4*)&W1b[(size_t)i * 8] = p;
        }
        if (gt < 64) ((unsigned int*)table)[gt] = 0u;          // 256 fp8 bytes of row 0
    }
    __threadfence();          // device-scope release (cross-XCD L2 writeback)
    grid.sync();

    // ---- phase A: h = tanh(x @ W1^T + b1) -> fp8 table (R10 body) ----
    const int wave = tid >> 6, lane = tid & 63;
    const int n0 = wave * 32;          // 8 waves = 8 n-bands of 32 cols
    const int lr = lane & 15;
    const int kg = lane >> 4;
    const int sw = lr & 7;

    for (int g = bx; g < NGRP; g += nb) {
        const int tok0 = g * BM;
        __syncthreads();               // protect xs reuse across grid-stride iterations

        // stage x: 32 rows x 256 f32 = 2048 f32x4 slots (64/row), coalesced,
        // bf16-packed, XOR-swizzled 16B granules
        #pragma unroll
        for (int p = 0; p < 4; ++p) {
            int s = p * 512 + tid;
            int row = s >> 6, k4 = s & 63;
            f32x4 v = *(const f32x4*)&x[(size_t)(tok0 + row) * DD + k4 * 4];
            uint2 pk;
            pk.x = pack2_bf16(v.x, v.y);
            pk.y = pack2_bf16(v.z, v.w);
            int gq = k4 >> 1;
            int gp = gq ^ (row & 7);
            *(uint2*)&xs[row * DD + gp * 8 + (k4 & 1) * 4] = pk;
        }
        __syncthreads();

        f32x4 acc[2][2];
        #pragma unroll
        for (int mf = 0; mf < 2; ++mf)
            #pragma unroll
            for (int nf = 0; nf < 2; ++nf)
                acc[mf][nf] = (f32x4){0.f, 0.f, 0.f, 0.f};

        const unsigned short* wrow0 = W1b + (size_t)(n0 + lr) * DD + kg * 8;
        const unsigned short* wrow1 = W1b + (size_t)(n0 + 16 + lr) * DD + kg * 8;

        #pragma unroll
        for (int c = 0; c < 8; ++c) {
            int gp8 = ((c * 4 + kg) ^ sw) * 8;
            bf16x8 af0 = *(const bf16x8*)&xs[lr * DD + gp8];
            bf16x8 af1 = *(const bf16x8*)&xs[(16 + lr) * DD + gp8];
            bf16x8 bf0 = *(const bf16x8*)&wrow0[c * 32];
            bf16x8 bf1 = *(const bf16x8*)&wrow1[c * 32];
            acc[0][0] = __builtin_amdgcn_mfma_f32_16x16x32_bf16(af0, bf0, acc[0][0], 0, 0, 0);
            acc[0][1] = __builtin_amdgcn_mfma_f32_16x16x32_bf16(af0, bf1, acc[0][1], 0, 0, 0);
            acc[1][0] = __builtin_amdgcn_mfma_f32_16x16x32_bf16(af1, bf0, acc[1][0], 0, 0, 0);
            acc[1][1] = __builtin_amdgcn_mfma_f32_16x16x32_bf16(af1, bf1, acc[1][1], 0, 0, 0);
        }

        float bj0 = b1[n0 + lr];
        float bj1 = b1[n0 + 16 + lr];

        __syncthreads();                               // af reads done: reuse xs as scratch
        unsigned char* sc = (unsigned char*)&xs[0];    // [32][272] fp8 scratch
        #pragma unroll
        for (int mf = 0; mf < 2; ++mf) {
            #pragma unroll
            for (int nf = 0; nf < 2; ++nf) {
                #pragma unroll
                for (int r = 0; r < 4; ++r) {
                    int row = mf * 16 + kg * 4 + r;    // C/D: col=lane&15, row=kg*4+reg
                    int col = n0 + nf * 16 + lr;
                    float v = fast_tanh(acc[mf][nf][r] + (nf ? bj1 : bj0));
                    sc[row * 272 + col] = f32_to_fp8(v);
                }
            }
        }
        __syncthreads();
        {
            int row = tid >> 4;                        // 32 rows x 256 B, 16 B/thread
            int off = (tid & 15) * 16;
            uint4 v = *(const uint4*)&sc[row * 272 + off];
            *(uint4*)&table[(size_t)(1 + tok0 + row) * DD + off] = v;
        }
    }
    __threadfence();          // device-scope release of table before cross-XCD reads
    grid.sync();

    // ---- phase B: fp8 gather + max over F + dot(w2) + bias + mask (R3 body) ----
    const int half = lane >> 5;
    const int cc   = lane & 31;
    const int d0   = cc * 8;

    for (int t0 = bx * 8; t0 < NTOK; t0 += nb * 8) {
        const int i = t0 + wave;                 // 8 waves = 8 tokens per iteration

        const int4* sp = (const int4*)(select_idx + (size_t)i * FF);
        int4 q0 = sp[0], q1 = sp[1];
        int rows[4];
        rows[0] = half ? q0.y : q0.x;
        rows[1] = half ? q0.w : q0.z;
        rows[2] = half ? q1.y : q1.x;
        rows[3] = half ? q1.w : q1.z;

        float m[8];
        #pragma unroll
        for (int j = 0; j < 8; ++j) m[j] = -INFINITY;

        #pragma unroll
        for (int it = 0; it < 4; ++it) {
            uint2 u = *(const uint2*)(table + (size_t)rows[it] * DD + d0);
            f32x2 a0 = __builtin_amdgcn_cvt_pk_f32_fp8(u.x, false);
            f32x2 a1 = __builtin_amdgcn_cvt_pk_f32_fp8(u.x, true);
            f32x2 a2 = __builtin_amdgcn_cvt_pk_f32_fp8(u.y, false);
            f32x2 a3 = __builtin_amdgcn_cvt_pk_f32_fp8(u.y, true);
            m[0] = fmaxf(m[0], a0.x); m[1] = fmaxf(m[1], a0.y);
            m[2] = fmaxf(m[2], a1.x); m[3] = fmaxf(m[3], a1.y);
            m[4] = fmaxf(m[4], a2.x); m[5] = fmaxf(m[5], a2.y);
            m[6] = fmaxf(m[6], a3.x); m[7] = fmaxf(m[7], a3.y);
        }

        #pragma unroll
        for (int j = 0; j < 8; ++j) m[j] = fmaxf(m[j], __shfl_xor(m[j], 32));

        f32x4 wa = *(const f32x4*)&w2[d0];
        f32x4 wb = *(const f32x4*)&w2[d0 + 4];
        float p = m[0] * wa.x + m[1] * wa.y + m[2] * wa.z + m[3] * wa.w
                + m[4] * wb.x + m[5] * wb.y + m[6] * wb.z + m[7] * wb.w;

        #pragma unroll
        for (int off = 16; off; off >>= 1) p += __shfl_xor(p, off);

        if (lane == 0) {
            float neg = word_mask[i] ? 0.f : -10000.f;
            out[i] = p + b2[0] + neg;
        }
    }
}

extern "C" void kernel_launch(void* const* d_in, const int* in_sizes, int n_in,
                              void* d_out, int out_size, void* d_ws, size_t ws_size,
                              hipStream_t stream) {
    const float* hs    = (const float*)d_in[0];   // [B,S,D] f32
    const int*   sidx  = (const int*)  d_in[1];   // [B,S,F] i32
    const int*   wmask = (const int*)  d_in[2];   // [B,S]   i32
    const float* W1    = (const float*)d_in[3];   // [D,D]   f32
    const float* b1    = (const float*)d_in[4];   // [D]     f32
    const float* w2    = (const float*)d_in[5];   // [D]     f32
    const float* b2    = (const float*)d_in[6];   // [1]     f32
    float* out = (float*)d_out;                   // [B,S]   f32

    unsigned char*  table = (unsigned char*)d_ws;                       // [1+NTOK, D] fp8
    unsigned short* W1b   = (unsigned short*)((char*)d_ws + (8u << 20)); // [D,D] bf16

    // co-residency guard for cooperative launch (grid-stride loops keep any grid correct)
    int nbpc = 0;
    if (hipOccupancyMaxActiveBlocksPerMultiprocessor(&nbpc, mega_kernel, 512, 0)
            != hipSuccess || nbpc < 1)
        nbpc = 1;
    int grid = nbpc * 256;
    if (grid > NGRP) grid = NGRP;   // 512 caps it; phase work is grid-strided anyway

    void* args[] = {(void*)&hs, (void*)&W1, (void*)&b1, (void*)&sidx, (void*)&wmask,
                    (void*)&w2, (void*)&b2, (void*)&table, (void*)&W1b, (void*)&out};
    hipLaunchCooperativeKernel(mega_kernel, dim3(grid), dim3(512), args, 0, stream);
}

// Round 5
// 97.169 us; speedup vs baseline: 2.3870x; 2.3870x over previous
//
#include <hip/hip_runtime.h>
#include <hip/hip_bf16.h>
#include <math.h>

// Problem constants
#define BB 8
#define SS 2048
#define DD 256
#define FF 8
#define NTOK (BB*SS)   // 16384

typedef __bf16 bf16x8 __attribute__((ext_vector_type(8)));
typedef float  f32x4  __attribute__((ext_vector_type(4)));
typedef float  f32x2  __attribute__((ext_vector_type(2)));

// ---------------- Kernel A: h = tanh(x @ W1^T + b1) -> fp8(e4m3) table via MFMA ----------
// R12 = R10 structure, W2B dispatch removed: B-fragments load straight from f32 W1
// (L2-hot, 256 KB/block = W1 exactly once per block) and pack to bf16 inline.
// [session model] dur_us ~= 44us ws-poison fill + ~8.5us per dispatch + kernel times;
// R11 proved grid.sync costs ~100us/barrier on 8 XCDs (232us total) -> cooperative
// fusion is dead; dispatch-count reduction must come from inline work like this.
// Structure: BM=32 tokens/block, ALL 256 cols per block -> x read from HBM exactly once
// (16 MB). grid 512 x 512thr = 2 blocks/CU, 4 waves/SIMD.
// x: coalesced f32x4 -> bf16 -> XOR-swizzled LDS (16 KB) -> conflict-free ds_read_b128.
// No mid-loop barriers: per wave the K-loop is 16 ds_read + 32 global loads + 32 MFMA.
#define BM 32

__device__ __forceinline__ unsigned pack2_bf16(float a, float b) {
    return (__float_as_uint(a) >> 16) | (__float_as_uint(b) & 0xFFFF0000u);
}
__device__ __forceinline__ float fast_tanh(float x) {
    float e = __expf(2.0f * x);
    return 1.0f - 2.0f * __builtin_amdgcn_rcpf(e + 1.0f);
}
__device__ __forceinline__ unsigned char f32_to_fp8(float v) {
    return (unsigned char)(__builtin_amdgcn_cvt_pk_fp8_f32(v, v, 0, false) & 0xFF);
}
__device__ __forceinline__ bf16x8 pack_bf16x8(f32x4 a, f32x4 b) {
    uint4 p;
    p.x = pack2_bf16(a.x, a.y); p.y = pack2_bf16(a.z, a.w);
    p.z = pack2_bf16(b.x, b.y); p.w = pack2_bf16(b.z, b.w);
    return *(bf16x8*)&p;
}

__global__ __launch_bounds__(512, 4) void gemm_tanh_kernel(
    const float* __restrict__ x, const float* __restrict__ W1,
    const float* __restrict__ b1, unsigned char* __restrict__ table)
{
    // x tile 32 x 256 bf16 = 16 KB; reused as fp8 scratch [32][272] in the epilogue
    __shared__ __align__(16) unsigned short xs[BM * DD];

    const int tid  = threadIdx.x;
    const int bx   = blockIdx.x;
    const int tok0 = bx * BM;

    // re-zero padding row 0 (256 fp8 bytes); ws is re-poisoned before every launch
    if (bx == 0 && tid < 64) ((unsigned int*)table)[tid] = 0u;

    const int wave = tid >> 6, lane = tid & 63;
    const int n0 = wave * 32;        // 8 waves = 8 n-bands of 32 cols; each wave does all 32 rows
    const int lr = lane & 15;
    const int kg = lane >> 4;
    const int sw = lr & 7;           // (row&7) same for row lr and lr+16

    // ---- stage x: 32 rows x 256 f32 = 2048 f32x4 slots (64 per row), coalesced,
    //      bf16-packed, XOR-swizzled 16B granules ----
    #pragma unroll
    for (int p = 0; p < 4; ++p) {
        int s = p * 512 + tid;
        int row = s >> 6, k4 = s & 63;             // 64 f32x4 slots per row
        f32x4 v = *(const f32x4*)&x[(size_t)(tok0 + row) * DD + k4 * 4];
        uint2 pk;
        pk.x = pack2_bf16(v.x, v.y);
        pk.y = pack2_bf16(v.z, v.w);
        int g  = k4 >> 1;                          // 16B granule 0..31 within row
        int gp = g ^ (row & 7);                    // swizzle: conflict-free b128 frag reads
        *(uint2*)&xs[row * DD + gp * 8 + (k4 & 1) * 4] = pk;
    }
    __syncthreads();

    f32x4 acc[2][2];
    #pragma unroll
    for (int mf = 0; mf < 2; ++mf)
        #pragma unroll
        for (int nf = 0; nf < 2; ++nf)
            acc[mf][nf] = (f32x4){0.f, 0.f, 0.f, 0.f};

    // B-fragment source rows in f32 W1 (converted inline; W1 is L2-hot: 256 KB/block)
    const float* wrowf0 = W1 + (size_t)(n0 + lr) * DD + kg * 8;       // nf=0
    const float* wrowf1 = W1 + (size_t)(n0 + 16 + lr) * DD + kg * 8;  // nf=1

    #pragma unroll
    for (int c = 0; c < 8; ++c) {
        int gp8 = ((c * 4 + kg) ^ sw) * 8;
        bf16x8 af0 = *(const bf16x8*)&xs[lr * DD + gp8];           // rows 0..15
        bf16x8 af1 = *(const bf16x8*)&xs[(16 + lr) * DD + gp8];    // rows 16..31
        f32x4 w0a = *(const f32x4*)&wrowf0[c * 32];
        f32x4 w0b = *(const f32x4*)&wrowf0[c * 32 + 4];
        f32x4 w1a = *(const f32x4*)&wrowf1[c * 32];
        f32x4 w1b = *(const f32x4*)&wrowf1[c * 32 + 4];
        bf16x8 bf0 = pack_bf16x8(w0a, w0b);
        bf16x8 bf1 = pack_bf16x8(w1a, w1b);
        acc[0][0] = __builtin_amdgcn_mfma_f32_16x16x32_bf16(af0, bf0, acc[0][0], 0, 0, 0);
        acc[0][1] = __builtin_amdgcn_mfma_f32_16x16x32_bf16(af0, bf1, acc[0][1], 0, 0, 0);
        acc[1][0] = __builtin_amdgcn_mfma_f32_16x16x32_bf16(af1, bf0, acc[1][0], 0, 0, 0);
        acc[1][1] = __builtin_amdgcn_mfma_f32_16x16x32_bf16(af1, bf1, acc[1][1], 0, 0, 0);
    }

    // ---- epilogue: bias + tanh -> fp8, LDS transpose, coalesced uint4 stores ----
    float bj0 = b1[n0 + lr];
    float bj1 = b1[n0 + 16 + lr];

    __syncthreads();                               // all af reads done: reuse xs as scratch
    unsigned char* sc = (unsigned char*)&xs[0];    // [32][272] fp8 scratch (8.5 KB)
    #pragma unroll
    for (int mf = 0; mf < 2; ++mf) {
        #pragma unroll
        for (int nf = 0; nf < 2; ++nf) {
            #pragma unroll
            for (int r = 0; r < 4; ++r) {
                int row = mf * 16 + kg * 4 + r;    // C/D layout: col=lane&15, row=kg*4+reg
                int col = n0 + nf * 16 + lr;
                float v = fast_tanh(acc[mf][nf][r] + (nf ? bj1 : bj0));
                sc[row * 272 + col] = f32_to_fp8(v);
            }
        }
    }
    __syncthreads();
    {
        int row = tid >> 4;                        // 32 rows x 256 B, 16 B per thread
        int off = (tid & 15) * 16;
        uint4 v = *(const uint4*)&sc[row * 272 + off];
        *(uint4*)&table[(size_t)(1 + tok0 + row) * DD + off] = v;
    }
}

// ---------------- Kernel B: fp8 gather + max over F + dot(w2) + bias + mask ----------------
// One wave per token. Halves of the wave take alternating f-rows; uint2 (8 fp8) per lane.
__global__ __launch_bounds__(256) void gather_score_kernel(
    const unsigned char* __restrict__ table,
    const int* __restrict__ select_idx,
    const int* __restrict__ word_mask,
    const float* __restrict__ w2,
    const float* __restrict__ b2,
    float* __restrict__ out)
{
    const int tid  = threadIdx.x;
    const int lane = tid & 63;
    const int wv   = tid >> 6;
    const int i    = blockIdx.x * 4 + wv;    // token
    const int half = lane >> 5;
    const int c    = lane & 31;
    const int d0   = c * 8;                  // 8 dims (8 B) per lane

    const int4* sp = (const int4*)(select_idx + (size_t)i * FF);
    int4 q0 = sp[0], q1 = sp[1];
    int rows[4];
    rows[0] = half ? q0.y : q0.x;
    rows[1] = half ? q0.w : q0.z;
    rows[2] = half ? q1.y : q1.x;
    rows[3] = half ? q1.w : q1.z;

    float m[8];
    #pragma unroll
    for (int j = 0; j < 8; ++j) m[j] = -INFINITY;

    #pragma unroll
    for (int it = 0; it < 4; ++it) {
        uint2 u = *(const uint2*)(table + (size_t)rows[it] * DD + d0);
        f32x2 a0 = __builtin_amdgcn_cvt_pk_f32_fp8(u.x, false);
        f32x2 a1 = __builtin_amdgcn_cvt_pk_f32_fp8(u.x, true);
        f32x2 a2 = __builtin_amdgcn_cvt_pk_f32_fp8(u.y, false);
        f32x2 a3 = __builtin_amdgcn_cvt_pk_f32_fp8(u.y, true);
        m[0] = fmaxf(m[0], a0.x); m[1] = fmaxf(m[1], a0.y);
        m[2] = fmaxf(m[2], a1.x); m[3] = fmaxf(m[3], a1.y);
        m[4] = fmaxf(m[4], a2.x); m[5] = fmaxf(m[5], a2.y);
        m[6] = fmaxf(m[6], a3.x); m[7] = fmaxf(m[7], a3.y);
    }

    #pragma unroll
    for (int j = 0; j < 8; ++j) m[j] = fmaxf(m[j], __shfl_xor(m[j], 32));

    f32x4 wa = *(const f32x4*)&w2[d0];
    f32x4 wb = *(const f32x4*)&w2[d0 + 4];
    float p = m[0] * wa.x + m[1] * wa.y + m[2] * wa.z + m[3] * wa.w
            + m[4] * wb.x + m[5] * wb.y + m[6] * wb.z + m[7] * wb.w;

    #pragma unroll
    for (int off = 16; off; off >>= 1) p += __shfl_xor(p, off);

    if (lane == 0) {
        float neg = word_mask[i] ? 0.f : -10000.f;
        out[i] = p + b2[0] + neg;
    }
}

extern "C" void kernel_launch(void* const* d_in, const int* in_sizes, int n_in,
                              void* d_out, int out_size, void* d_ws, size_t ws_size,
                              hipStream_t stream) {
    const float* hs    = (const float*)d_in[0];   // [B,S,D] f32
    const int*   sidx  = (const int*)  d_in[1];   // [B,S,F] i32
    const int*   wmask = (const int*)  d_in[2];   // [B,S]   i32
    const float* W1    = (const float*)d_in[3];   // [D,D]   f32
    const float* b1    = (const float*)d_in[4];   // [D]     f32
    const float* w2    = (const float*)d_in[5];   // [D]     f32
    const float* b2    = (const float*)d_in[6];   // [1]     f32
    float* out = (float*)d_out;                   // [B,S]   f32

    unsigned char* table = (unsigned char*)d_ws;  // [1+NTOK, D] fp8 e4m3 (~4.2 MB)

    gemm_tanh_kernel<<<NTOK / BM, 512, 0, stream>>>(hs, W1, b1, table);
    gather_score_kernel<<<NTOK / 4, 256, 0, stream>>>(table, sidx, wmask, w2, b2, out);
}

// Round 6
// 90.514 us; speedup vs baseline: 2.5625x; 1.0735x over previous
//
#include <hip/hip_runtime.h>
#include <hip/hip_bf16.h>
#include <math.h>

// Problem constants
#define BB 8
#define SS 2048
#define DD 256
#define FF 8
#define NTOK (BB*SS)   // 16384

typedef __bf16 bf16x8 __attribute__((ext_vector_type(8)));
typedef float  f32x4  __attribute__((ext_vector_type(4)));
typedef float  f32x2  __attribute__((ext_vector_type(2)));

// ---------------- Kernel A: h = tanh(x @ W1^T + b1) -> fp8(e4m3) table via MFMA ----------
// R13. Session evidence:
//  - R8 (scattered x direct-to-frag) A~24us; R12 (scattered W direct-to-frag) A~24.6us
//    => 16-lanes-x-16-rows scattered global fragment loads cost ~+16us. NEVER do them.
//  - R10 (x-once + bf16 W, 3 dispatches) = 90.5; R4 (x-4x redundant, 2 disp) = 87.6;
//    fit: dispatch oh ~8.5us, A10 ~8.4us => x-once works IF loads are well-formed.
//  - R11: grid.sync ~100us/barrier on 8 XCDs. Cooperative fusion is dead.
// R13 = x-once + ALL global loads thread-linear coalesced + ALL fragment reads from
// XOR-swizzled LDS + no extra dispatch. W1 staged through LDS in 4 chunks of 64 rows
// (f32 coalesced -> inline bf16 pack -> swizzled store), single-buffered, with the next
// chunk register-prefetched before each compute phase. LDS 16KB(x)+32KB(W)=48KB/block
// -> 2 blocks/CU at launch_bounds(512,4). Per-CU floor ~4-6us.
#define BM 32
#define WCH 64          // W chunk rows (output cols per chunk)
#define NCH (DD/WCH)    // 4

__device__ __forceinline__ unsigned pack2_bf16(float a, float b) {
    return (__float_as_uint(a) >> 16) | (__float_as_uint(b) & 0xFFFF0000u);
}
__device__ __forceinline__ float fast_tanh(float x) {
    float e = __expf(2.0f * x);
    return 1.0f - 2.0f * __builtin_amdgcn_rcpf(e + 1.0f);
}
__device__ __forceinline__ unsigned char f32_to_fp8(float v) {
    return (unsigned char)(__builtin_amdgcn_cvt_pk_fp8_f32(v, v, 0, false) & 0xFF);
}

__global__ __launch_bounds__(512, 4) void gemm_tanh_kernel(
    const float* __restrict__ x, const float* __restrict__ W1,
    const float* __restrict__ b1, unsigned char* __restrict__ table)
{
    __shared__ __align__(16) unsigned short xs[BM * DD];    // 16 KB (reused as fp8 scratch)
    __shared__ __align__(16) unsigned short wb[WCH * DD];   // 32 KB, single-buffered

    const int tid  = threadIdx.x;
    const int bx   = blockIdx.x;
    const int tok0 = bx * BM;

    // re-zero padding row 0 (256 fp8 bytes); ws is re-poisoned before every launch
    if (bx == 0 && tid < 64) ((unsigned int*)table)[tid] = 0u;

    const int wave = tid >> 6, lane = tid & 63;
    const int mf = wave >> 2;        // 0..1: which 16-row m-frag this wave owns
    const int nf = wave & 3;         // 0..3: which 16-col n-frag within the chunk
    const int lr = lane & 15;
    const int kg = lane >> 4;
    const int sw = lr & 7;           // swizzle key; == (row&7) for rows lr, 16+lr, nf*16+lr

    // ---- W chunk staging: thread-linear coalesced (1 KB contiguous per wave-instr) ----
    f32x4 wr[8];
    auto wload = [&](int nc) {
        #pragma unroll
        for (int p = 0; p < 8; ++p) {
            int s = p * 512 + tid;                 // 4096 f32x4 slots (64 per row)
            int row = s >> 6, k4 = s & 63;
            wr[p] = *(const f32x4*)&W1[(size_t)(nc * WCH + row) * DD + k4 * 4];
        }
    };
    auto wstore = [&]() {
        #pragma unroll
        for (int p = 0; p < 8; ++p) {
            int s = p * 512 + tid;
            int row = s >> 6, k4 = s & 63;
            uint2 pk;
            pk.x = pack2_bf16(wr[p].x, wr[p].y);
            pk.y = pack2_bf16(wr[p].z, wr[p].w);
            int gp = (k4 >> 1) ^ (row & 7);        // XOR-swizzled 16B granule
            *(uint2*)&wb[row * DD + gp * 8 + (k4 & 1) * 4] = pk;
        }
    };

    wload(0);                                      // W chunk 0 in flight first

    // ---- stage x: 32 rows x 256 f32 = 2048 f32x4 slots (64/row), coalesced,
    //      bf16-packed, XOR-swizzled (proven R10 path) ----
    #pragma unroll
    for (int p = 0; p < 4; ++p) {
        int s = p * 512 + tid;
        int row = s >> 6, k4 = s & 63;
        f32x4 v = *(const f32x4*)&x[(size_t)(tok0 + row) * DD + k4 * 4];
        uint2 pk;
        pk.x = pack2_bf16(v.x, v.y);
        pk.y = pack2_bf16(v.z, v.w);
        int gp = (k4 >> 1) ^ (row & 7);
        *(uint2*)&xs[row * DD + gp * 8 + (k4 & 1) * 4] = pk;
    }

    wstore();                                      // W0 -> LDS (waits its loads only)
    __syncthreads();

    f32x4 acc[NCH];
    #pragma unroll
    for (int nc = 0; nc < NCH; ++nc) acc[nc] = (f32x4){0.f, 0.f, 0.f, 0.f};

    const int arow = mf * 16 + lr;                 // x row this wave's A-frag reads
    const int nrow = nf * 16 + lr;                 // chunk-local W row (B-frag)

    #pragma unroll
    for (int nc = 0; nc < NCH; ++nc) {
        if (nc + 1 < NCH) wload(nc + 1);           // next chunk's globals in flight early

        #pragma unroll
        for (int c = 0; c < 8; ++c) {
            int gp8 = ((c * 4 + kg) ^ sw) * 8;
            bf16x8 af = *(const bf16x8*)&xs[arow * DD + gp8];
            bf16x8 bf = *(const bf16x8*)&wb[nrow * DD + gp8];
            acc[nc] = __builtin_amdgcn_mfma_f32_16x16x32_bf16(af, bf, acc[nc], 0, 0, 0);
        }
        __syncthreads();                           // all reads of wb done
        if (nc + 1 < NCH) {
            wstore();                              // overwrite wb with next chunk
            __syncthreads();
        }
    }

    // ---- epilogue: bias + tanh -> fp8, LDS transpose, coalesced uint4 stores ----
    float bj[NCH];
    #pragma unroll
    for (int nc = 0; nc < NCH; ++nc) bj[nc] = b1[nc * WCH + nf * 16 + lr];

    // last chunk ended with a barrier and no wstore: xs is safe to reuse immediately
    unsigned char* sc = (unsigned char*)&xs[0];    // [32][272] fp8 scratch (8.5 KB)
    #pragma unroll
    for (int nc = 0; nc < NCH; ++nc) {
        #pragma unroll
        for (int r = 0; r < 4; ++r) {
            int row = mf * 16 + kg * 4 + r;        // C/D layout: col=lane&15, row=kg*4+reg
            int col = nc * WCH + nf * 16 + lr;
            float v = fast_tanh(acc[nc][r] + bj[nc]);
            sc[row * 272 + col] = f32_to_fp8(v);
        }
    }
    __syncthreads();
    {
        int row = tid >> 4;                        // 32 rows x 256 B, 16 B per thread
        int off = (tid & 15) * 16;
        uint4 v = *(const uint4*)&sc[row * 272 + off];
        *(uint4*)&table[(size_t)(1 + tok0 + row) * DD + off] = v;
    }
}

// ---------------- Kernel B: fp8 gather + max over F + dot(w2) + bias + mask ----------------
// One wave per token. Halves of the wave take alternating f-rows; uint2 (8 fp8) per lane.
__global__ __launch_bounds__(256) void gather_score_kernel(
    const unsigned char* __restrict__ table,
    const int* __restrict__ select_idx,
    const int* __restrict__ word_mask,
    const float* __restrict__ w2,
    const float* __restrict__ b2,
    float* __restrict__ out)
{
    const int tid  = threadIdx.x;
    const int lane = tid & 63;
    const int wv   = tid >> 6;
    const int i    = blockIdx.x * 4 + wv;    // token
    const int half = lane >> 5;
    const int c    = lane & 31;
    const int d0   = c * 8;                  // 8 dims (8 B) per lane

    const int4* sp = (const int4*)(select_idx + (size_t)i * FF);
    int4 q0 = sp[0], q1 = sp[1];
    int rows[4];
    rows[0] = half ? q0.y : q0.x;
    rows[1] = half ? q0.w : q0.z;
    rows[2] = half ? q1.y : q1.x;
    rows[3] = half ? q1.w : q1.z;

    float m[8];
    #pragma unroll
    for (int j = 0; j < 8; ++j) m[j] = -INFINITY;

    #pragma unroll
    for (int it = 0; it < 4; ++it) {
        uint2 u = *(const uint2*)(table + (size_t)rows[it] * DD + d0);
        f32x2 a0 = __builtin_amdgcn_cvt_pk_f32_fp8(u.x, false);
        f32x2 a1 = __builtin_amdgcn_cvt_pk_f32_fp8(u.x, true);
        f32x2 a2 = __builtin_amdgcn_cvt_pk_f32_fp8(u.y, false);
        f32x2 a3 = __builtin_amdgcn_cvt_pk_f32_fp8(u.y, true);
        m[0] = fmaxf(m[0], a0.x); m[1] = fmaxf(m[1], a0.y);
        m[2] = fmaxf(m[2], a1.x); m[3] = fmaxf(m[3], a1.y);
        m[4] = fmaxf(m[4], a2.x); m[5] = fmaxf(m[5], a2.y);
        m[6] = fmaxf(m[6], a3.x); m[7] = fmaxf(m[7], a3.y);
    }

    #pragma unroll
    for (int j = 0; j < 8; ++j) m[j] = fmaxf(m[j], __shfl_xor(m[j], 32));

    f32x4 wa = *(const f32x4*)&w2[d0];
    f32x4 wb = *(const f32x4*)&w2[d0 + 4];
    float p = m[0] * wa.x + m[1] * wa.y + m[2] * wa.z + m[3] * wa.w
            + m[4] * wb.x + m[5] * wb.y + m[6] * wb.z + m[7] * wb.w;

    #pragma unroll
    for (int off = 16; off; off >>= 1) p += __shfl_xor(p, off);

    if (lane == 0) {
        float neg = word_mask[i] ? 0.f : -10000.f;
        out[i] = p + b2[0] + neg;
    }
}

extern "C" void kernel_launch(void* const* d_in, const int* in_sizes, int n_in,
                              void* d_out, int out_size, void* d_ws, size_t ws_size,
                              hipStream_t stream) {
    const float* hs    = (const float*)d_in[0];   // [B,S,D] f32
    const int*   sidx  = (const int*)  d_in[1];   // [B,S,F] i32
    const int*   wmask = (const int*)  d_in[2];   // [B,S]   i32
    const float* W1    = (const float*)d_in[3];   // [D,D]   f32
    const float* b1    = (const float*)d_in[4];   // [D]     f32
    const float* w2    = (const float*)d_in[5];   // [D]     f32
    const float* b2    = (const float*)d_in[6];   // [1]     f32
    float* out = (float*)d_out;                   // [B,S]   f32

    unsigned char* table = (unsigned char*)d_ws;  // [1+NTOK, D] fp8 e4m3 (~4.2 MB)

    gemm_tanh_kernel<<<NTOK / BM, 512, 0, stream>>>(hs, W1, b1, table);
    gather_score_kernel<<<NTOK / 4, 256, 0, stream>>>(table, sidx, wmask, w2, b2, out);
}

// Round 7
// 89.525 us; speedup vs baseline: 2.5908x; 1.0110x over previous
//
#include <hip/hip_runtime.h>
#include <hip/hip_bf16.h>
#include <math.h>

// Problem constants
#define BB 8
#define SS 2048
#define DD 256
#define FF 8
#define NTOK (BB*SS)   // 16384

typedef __bf16 bf16x8 __attribute__((ext_vector_type(8)));
typedef float  f32x4  __attribute__((ext_vector_type(4)));
typedef float  f32x2  __attribute__((ext_vector_type(2)));

// ---------------- Kernel A: h = tanh(x @ W1^T + b1) -> fp8(e4m3) table via MFMA ----------
// R14. Session ledger:
//  - R8/R12: scattered f32 direct-to-frag global loads are catastrophic (~+16us). Never.
//  - R10: x-once + bf16-W direct frags: A=8.4us but needs a W2B dispatch (oh ~8.5us).
//  - R13: BM=32 + f32-W through LDS single-buffered: A~18us. TWO causes: 512 blocks
//    each read ALL of W1 (f32: 128 MB aggregate L2), and per-chunk delivery (0.9us)
//    exposed behind 2 barriers with only ~0.2us compute to hide it.
//  - R11: grid.sync ~100us/barrier on 8 XCDs. Cooperative fusion dead.
// R14: BM=64, 1024-thr block (16 waves = 4/SIMD), grid 256 = 1 block/CU.
//  - x read once (16 MB HBM), coalesced f32x4 -> bf16 -> XOR-swizzled LDS (32 KB).
//  - W1 f32 -> LDS in 4 chunks of 64 rows, coalesced + inline pack, single-buffered
//    32 KB (LDS total 64 KB). W aggregate halves to 64 MB; per-CU delivery 256 KB
//    (~1.9us) issued a chunk ahead. All fragment reads from swizzled LDS.
#define BM 64
#define WCH 64          // W chunk rows (output cols per chunk)
#define NCH (DD/WCH)    // 4

__device__ __forceinline__ unsigned pack2_bf16(float a, float b) {
    return (__float_as_uint(a) >> 16) | (__float_as_uint(b) & 0xFFFF0000u);
}
__device__ __forceinline__ float fast_tanh(float x) {
    float e = __expf(2.0f * x);
    return 1.0f - 2.0f * __builtin_amdgcn_rcpf(e + 1.0f);
}
__device__ __forceinline__ unsigned char f32_to_fp8(float v) {
    return (unsigned char)(__builtin_amdgcn_cvt_pk_fp8_f32(v, v, 0, false) & 0xFF);
}

__global__ __launch_bounds__(1024, 4) void gemm_tanh_kernel(
    const float* __restrict__ x, const float* __restrict__ W1,
    const float* __restrict__ b1, unsigned char* __restrict__ table)
{
    __shared__ __align__(16) unsigned short xs[BM * DD];    // 32 KB (reused as fp8 scratch)
    __shared__ __align__(16) unsigned short wt[WCH * DD];   // 32 KB, single-buffered

    const int tid  = threadIdx.x;
    const int bx   = blockIdx.x;
    const int tok0 = bx * BM;

    // re-zero padding row 0 (256 fp8 bytes); ws is re-poisoned before every launch
    if (bx == 0 && tid < 64) ((unsigned int*)table)[tid] = 0u;

    const int wave = tid >> 6, lane = tid & 63;
    const int wm  = wave >> 2;       // 0..3: 16-row m-frag
    const int wnf = wave & 3;        // 0..3: 16-col n-frag within the 64-col chunk
    const int lr = lane & 15;
    const int kg = lane >> 4;
    const int sw = lr & 7;           // swizzle key == (row&7) for rows wm*16+lr / wnf*16+lr

    // ---- W chunk staging: 64 rows x 64 f32x4 slots = 4096 slots, 4 per thread ----
    f32x4 wr[4];
    auto wload = [&](int nc) {
        #pragma unroll
        for (int p = 0; p < 4; ++p) {
            int s = p * 1024 + tid;
            int row = s >> 6, k4 = s & 63;
            wr[p] = *(const f32x4*)&W1[(size_t)(nc * WCH + row) * DD + k4 * 4];
        }
    };
    auto wstore = [&]() {
        #pragma unroll
        for (int p = 0; p < 4; ++p) {
            int s = p * 1024 + tid;
            int row = s >> 6, k4 = s & 63;
            uint2 pk;
            pk.x = pack2_bf16(wr[p].x, wr[p].y);
            pk.y = pack2_bf16(wr[p].z, wr[p].w);
            int gp = (k4 >> 1) ^ (row & 7);        // XOR-swizzled 16B granule
            *(uint2*)&wt[row * DD + gp * 8 + (k4 & 1) * 4] = pk;
        }
    };

    wload(0);                                      // W chunk 0 in flight first

    // ---- stage x: 64 rows x 64 f32x4 slots = 4096 slots, 4/thread, coalesced,
    //      bf16-packed, XOR-swizzled (proven path) ----
    #pragma unroll
    for (int p = 0; p < 4; ++p) {
        int s = p * 1024 + tid;
        int row = s >> 6, k4 = s & 63;
        f32x4 v = *(const f32x4*)&x[(size_t)(tok0 + row) * DD + k4 * 4];
        uint2 pk;
        pk.x = pack2_bf16(v.x, v.y);
        pk.y = pack2_bf16(v.z, v.w);
        int gp = (k4 >> 1) ^ (row & 7);
        *(uint2*)&xs[row * DD + gp * 8 + (k4 & 1) * 4] = pk;
    }

    wstore();                                      // W0 -> LDS
    __syncthreads();

    f32x4 acc[NCH];
    #pragma unroll
    for (int nc = 0; nc < NCH; ++nc) acc[nc] = (f32x4){0.f, 0.f, 0.f, 0.f};

    const int arow = wm * 16 + lr;                 // x row of this wave's A-frag
    const int nrow = wnf * 16 + lr;                // chunk-local W row (B-frag)

    #pragma unroll
    for (int nc = 0; nc < NCH; ++nc) {
        if (nc + 1 < NCH) wload(nc + 1);           // next chunk's globals in flight early

        #pragma unroll
        for (int c = 0; c < 8; ++c) {
            int gp8 = ((c * 4 + kg) ^ sw) * 8;
            bf16x8 af = *(const bf16x8*)&xs[arow * DD + gp8];
            bf16x8 bf = *(const bf16x8*)&wt[nrow * DD + gp8];
            acc[nc] = __builtin_amdgcn_mfma_f32_16x16x32_bf16(af, bf, acc[nc], 0, 0, 0);
        }
        __syncthreads();                           // all reads of wt done
        if (nc + 1 < NCH) {
            wstore();                              // overwrite wt with next chunk
            __syncthreads();
        }
    }

    // ---- epilogue: bias + tanh -> fp8, LDS transpose, coalesced uint4 stores ----
    float bj[NCH];
    #pragma unroll
    for (int nc = 0; nc < NCH; ++nc) bj[nc] = b1[nc * WCH + wnf * 16 + lr];

    // last chunk ended at a barrier with no wstore: xs safe to reuse as scratch
    unsigned char* sc = (unsigned char*)&xs[0];    // [64][272] fp8 scratch (17.4 KB)
    #pragma unroll
    for (int nc = 0; nc < NCH; ++nc) {
        #pragma unroll
        for (int r = 0; r < 4; ++r) {
            int row = wm * 16 + kg * 4 + r;        // C/D layout: col=lane&15, row=kg*4+reg
            int col = nc * WCH + wnf * 16 + lr;
            float v = fast_tanh(acc[nc][r] + bj[nc]);
            sc[row * 272 + col] = f32_to_fp8(v);
        }
    }
    __syncthreads();
    {
        int row = tid >> 4;                        // 64 rows x 256 B, 16 B per thread
        int off = (tid & 15) * 16;
        uint4 v = *(const uint4*)&sc[row * 272 + off];
        *(uint4*)&table[(size_t)(1 + tok0 + row) * DD + off] = v;
    }
}

// ---------------- Kernel B: fp8 gather + max over F + dot(w2) + bias + mask ----------------
// R14: 2048 blocks (was 4096); each wave handles TWO tokens with all 8 gather loads
// manually interleaved -> 2x memory-level parallelism, half the dispatch/drain cost.
__global__ __launch_bounds__(256) void gather_score_kernel(
    const unsigned char* __restrict__ table,
    const int* __restrict__ select_idx,
    const int* __restrict__ word_mask,
    const float* __restrict__ w2,
    const float* __restrict__ b2,
    float* __restrict__ out)
{
    const int tid  = threadIdx.x;
    const int lane = tid & 63;
    const int wv   = tid >> 6;
    const int iA   = blockIdx.x * 8 + wv * 2;     // tokens iA, iA+1
    const int iB   = iA + 1;
    const int half = lane >> 5;
    const int c    = lane & 31;
    const int d0   = c * 8;                        // 8 dims (8 B) per lane

    const int4* spA = (const int4*)(select_idx + (size_t)iA * FF);
    const int4* spB = (const int4*)(select_idx + (size_t)iB * FF);
    int4 qa0 = spA[0], qa1 = spA[1];
    int4 qb0 = spB[0], qb1 = spB[1];
    int rA[4], rB[4];
    rA[0] = half ? qa0.y : qa0.x;  rA[1] = half ? qa0.w : qa0.z;
    rA[2] = half ? qa1.y : qa1.x;  rA[3] = half ? qa1.w : qa1.z;
    rB[0] = half ? qb0.y : qb0.x;  rB[1] = half ? qb0.w : qb0.z;
    rB[2] = half ? qb1.y : qb1.x;  rB[3] = half ? qb1.w : qb1.z;

    uint2 uA[4], uB[4];                            // all 8 gathers in flight together
    #pragma unroll
    for (int it = 0; it < 4; ++it) {
        uA[it] = *(const uint2*)(table + (size_t)rA[it] * DD + d0);
        uB[it] = *(const uint2*)(table + (size_t)rB[it] * DD + d0);
    }

    float mA[8], mB[8];
    #pragma unroll
    for (int j = 0; j < 8; ++j) { mA[j] = -INFINITY; mB[j] = -INFINITY; }

    #pragma unroll
    for (int it = 0; it < 4; ++it) {
        f32x2 a0 = __builtin_amdgcn_cvt_pk_f32_fp8(uA[it].x, false);
        f32x2 a1 = __builtin_amdgcn_cvt_pk_f32_fp8(uA[it].x, true);
        f32x2 a2 = __builtin_amdgcn_cvt_pk_f32_fp8(uA[it].y, false);
        f32x2 a3 = __builtin_amdgcn_cvt_pk_f32_fp8(uA[it].y, true);
        mA[0] = fmaxf(mA[0], a0.x); mA[1] = fmaxf(mA[1], a0.y);
        mA[2] = fmaxf(mA[2], a1.x); mA[3] = fmaxf(mA[3], a1.y);
        mA[4] = fmaxf(mA[4], a2.x); mA[5] = fmaxf(mA[5], a2.y);
        mA[6] = fmaxf(mA[6], a3.x); mA[7] = fmaxf(mA[7], a3.y);
        f32x2 b0 = __builtin_amdgcn_cvt_pk_f32_fp8(uB[it].x, false);
        f32x2 b1v = __builtin_amdgcn_cvt_pk_f32_fp8(uB[it].x, true);
        f32x2 b2v = __builtin_amdgcn_cvt_pk_f32_fp8(uB[it].y, false);
        f32x2 b3 = __builtin_amdgcn_cvt_pk_f32_fp8(uB[it].y, true);
        mB[0] = fmaxf(mB[0], b0.x); mB[1] = fmaxf(mB[1], b0.y);
        mB[2] = fmaxf(mB[2], b1v.x); mB[3] = fmaxf(mB[3], b1v.y);
        mB[4] = fmaxf(mB[4], b2v.x); mB[5] = fmaxf(mB[5], b2v.y);
        mB[6] = fmaxf(mB[6], b3.x); mB[7] = fmaxf(mB[7], b3.y);
    }

    #pragma unroll
    for (int j = 0; j < 8; ++j) {
        mA[j] = fmaxf(mA[j], __shfl_xor(mA[j], 32));
        mB[j] = fmaxf(mB[j], __shfl_xor(mB[j], 32));
    }

    f32x4 wa = *(const f32x4*)&w2[d0];
    f32x4 wb = *(const f32x4*)&w2[d0 + 4];
    float pA = mA[0] * wa.x + mA[1] * wa.y + mA[2] * wa.z + mA[3] * wa.w
             + mA[4] * wb.x + mA[5] * wb.y + mA[6] * wb.z + mA[7] * wb.w;
    float pB = mB[0] * wa.x + mB[1] * wa.y + mB[2] * wa.z + mB[3] * wa.w
             + mB[4] * wb.x + mB[5] * wb.y + mB[6] * wb.z + mB[7] * wb.w;

    #pragma unroll
    for (int off = 16; off; off >>= 1) {
        pA += __shfl_xor(pA, off);
        pB += __shfl_xor(pB, off);
    }

    if (lane == 0) {
        float negA = word_mask[iA] ? 0.f : -10000.f;
        float negB = word_mask[iB] ? 0.f : -10000.f;
        out[iA] = pA + b2[0] + negA;
        out[iB] = pB + b2[0] + negB;
    }
}

extern "C" void kernel_launch(void* const* d_in, const int* in_sizes, int n_in,
                              void* d_out, int out_size, void* d_ws, size_t ws_size,
                              hipStream_t stream) {
    const float* hs    = (const float*)d_in[0];   // [B,S,D] f32
    const int*   sidx  = (const int*)  d_in[1];   // [B,S,F] i32
    const int*   wmask = (const int*)  d_in[2];   // [B,S]   i32
    const float* W1    = (const float*)d_in[3];   // [D,D]   f32
    const float* b1    = (const float*)d_in[4];   // [D]     f32
    const float* w2    = (const float*)d_in[5];   // [D]     f32
    const float* b2    = (const float*)d_in[6];   // [1]     f32
    float* out = (float*)d_out;                   // [B,S]   f32

    unsigned char* table = (unsigned char*)d_ws;  // [1+NTOK, D] fp8 e4m3 (~4.2 MB)

    gemm_tanh_kernel<<<NTOK / BM, 1024, 0, stream>>>(hs, W1, b1, table);
    gather_score_kernel<<<NTOK / 8, 256, 0, stream>>>(table, sidx, wmask, w2, b2, out);
}

// Round 8
// 85.968 us; speedup vs baseline: 2.6980x; 1.0414x over previous
//
#include <hip/hip_runtime.h>
#include <hip/hip_bf16.h>
#include <math.h>

// Problem constants
#define BB 8
#define SS 2048
#define DD 256
#define FF 8
#define NTOK (BB*SS)   // 16384

typedef __bf16 bf16x8 __attribute__((ext_vector_type(8)));
typedef float  f32x4  __attribute__((ext_vector_type(4)));
typedef float  f32x2  __attribute__((ext_vector_type(2)));

// ---------------- Kernel A: h = tanh(x @ W1^T + b1) -> fp8(e4m3) table via MFMA ----------
// R15 = R4's verified kernel (best measured A) with ONE change: the blockIdx decode.
// Session ledger:
//  - R4: tokgrp=bx&127 put the 4 n-siblings of a token group on the same XCD but 128
//    blockIdx APART -> ~16 MB of other tiles flow through that XCD-L2 (4 MB) between
//    siblings -> x-tile evicted -> no dedup -> 64 MB x HBM traffic -> A~15us.
//  - R8/R12: scattered direct-to-frag global loads: +16us. Never.
//  - R10/R13/R14: x-once rewrites all land A~17-18us (LDS/serialization losses) or
//    need a +9.5us extra dispatch. Structural rewrites lose to R4's simple loop.
//  - R11: grid.sync ~100us/barrier. Dead.
// R15 decode: bx = g*32 + n*8 + x  ->  tokgrp = g*8+x, nblk = n. Siblings are 8 apart
// (same XCD under round-robin bx%8) AND within 24 dispatch slots (co-resident), so
// siblings 1..3 find the 128 KB x-tile still in the 4 MB XCD-L2.
#define BM 128
#define BN 64
#define BK 64
#define NSTEP (DD/BK)   // 4
#define XS 72           // LDS row stride in ushorts (BK + 8 pad): 144 B, 16B-aligned

__device__ __forceinline__ float fast_tanh(float x) {
    float e = __expf(2.0f * x);
    return 1.0f - 2.0f * __builtin_amdgcn_rcpf(e + 1.0f);
}

__device__ __forceinline__ unsigned pack2_bf16(float a, float b) {
    return (__float_as_uint(a) >> 16) | (__float_as_uint(b) & 0xFFFF0000u);
}

__device__ __forceinline__ unsigned char f32_to_fp8(float v) {
    return (unsigned char)(__builtin_amdgcn_cvt_pk_fp8_f32(v, v, 0, false) & 0xFF);
}

__global__ __launch_bounds__(512, 4) void gemm_tanh_kernel(
    const float* __restrict__ x, const float* __restrict__ W1,
    const float* __restrict__ b1, unsigned char* __restrict__ table)
{
    __shared__ __align__(16) unsigned short xs[2][BM * XS];   // 36 KB (reused as fp8 scratch)
    __shared__ __align__(16) unsigned short wsb[2][BN * XS];  // 18 KB

    const int tid  = threadIdx.x;
    const int bx   = blockIdx.x;
    // R15 decode: same-XCD siblings co-scheduled (see header comment)
    const int tokgrp = ((bx >> 5) << 3) | (bx & 7);   // 0..127
    const int nblk   = (bx >> 3) & 3;                 // 0..3
    const int tok0 = tokgrp * BM;
    const int n0   = nblk * BN;

    // re-zero padding row 0 (256 fp8 bytes); ws is re-poisoned before every launch
    if (bx == 0 && tid < 64) ((unsigned int*)table)[tid] = 0u;

    const int wave = tid >> 6, lane = tid & 63;
    const int wm = wave >> 1;        // 0..3: 32-row m band
    const int wn = wave & 1;         // 0..1: 32-col n band
    const int lr = lane & 15;
    const int kg = lane >> 4;

    f32x4 xr[4], wr[2];              // staging registers

    auto load_chunk = [&](int k0) {
        #pragma unroll
        for (int rep = 0; rep < 4; ++rep) {            // x: 128 rows x 16 f32x4 = 2048 slots
            int slot = rep * 512 + tid;
            int row = slot >> 4, kc = slot & 15;
            xr[rep] = *(const f32x4*)&x[(size_t)(tok0 + row) * DD + k0 + kc * 4];
        }
        #pragma unroll
        for (int rep = 0; rep < 2; ++rep) {            // W1: 64 rows x 16 f32x4 = 1024 slots
            int slot = rep * 512 + tid;
            int row = slot >> 4, kc = slot & 15;
            wr[rep] = *(const f32x4*)&W1[(size_t)(n0 + row) * DD + k0 + kc * 4];
        }
    };
    auto store_lds = [&](int buf) {
        #pragma unroll
        for (int rep = 0; rep < 4; ++rep) {
            int slot = rep * 512 + tid;
            int row = slot >> 4, kc = slot & 15;
            uint2 p;
            p.x = pack2_bf16(xr[rep].x, xr[rep].y);
            p.y = pack2_bf16(xr[rep].z, xr[rep].w);
            *(uint2*)&xs[buf][row * XS + kc * 4] = p;
        }
        #pragma unroll
        for (int rep = 0; rep < 2; ++rep) {
            int slot = rep * 512 + tid;
            int row = slot >> 4, kc = slot & 15;
            uint2 p;
            p.x = pack2_bf16(wr[rep].x, wr[rep].y);
            p.y = pack2_bf16(wr[rep].z, wr[rep].w);
            *(uint2*)&wsb[buf][row * XS + kc * 4] = p;
        }
    };

    f32x4 acc[2][2];
    #pragma unroll
    for (int mf = 0; mf < 2; ++mf)
        #pragma unroll
        for (int nf = 0; nf < 2; ++nf)
            acc[mf][nf] = (f32x4){0.f, 0.f, 0.f, 0.f};

    load_chunk(0);
    store_lds(0);

    for (int s = 0; s < NSTEP; ++s) {
        __syncthreads();                               // one barrier per step
        const int buf = s & 1;
        if (s + 1 < NSTEP) load_chunk((s + 1) * BK);   // global loads in flight early

        bf16x8 af[2][2], bfr[2][2];                    // [k-chunk][frag]
        #pragma unroll
        for (int c = 0; c < 2; ++c) {
            #pragma unroll
            for (int mf = 0; mf < 2; ++mf) {
                int m = wm * 32 + mf * 16 + lr;
                af[c][mf] = *(const bf16x8*)&xs[buf][m * XS + c * 32 + kg * 8];
            }
            #pragma unroll
            for (int nf = 0; nf < 2; ++nf) {
                int n = wn * 32 + nf * 16 + lr;
                bfr[c][nf] = *(const bf16x8*)&wsb[buf][n * XS + c * 32 + kg * 8];
            }
        }
        if (s + 1 < NSTEP) store_lds(buf ^ 1);         // buf^1 reads drained at this step's barrier

        #pragma unroll
        for (int c = 0; c < 2; ++c)
            #pragma unroll
            for (int mf = 0; mf < 2; ++mf)
                #pragma unroll
                for (int nf = 0; nf < 2; ++nf)
                    acc[mf][nf] = __builtin_amdgcn_mfma_f32_16x16x32_bf16(
                        af[c][mf], bfr[c][nf], acc[mf][nf], 0, 0, 0);
    }

    // ---- epilogue: bias + tanh -> fp8, LDS transpose, coalesced uint4 stores ----
    float bj[2];
    #pragma unroll
    for (int nf = 0; nf < 2; ++nf) bj[nf] = b1[n0 + wn * 32 + nf * 16 + lr];

    __syncthreads();                                   // safe to reuse xs as scratch
    unsigned char* sc = (unsigned char*)&xs[0][0];     // [BM][80] fp8 scratch (10 KB)
    #pragma unroll
    for (int mf = 0; mf < 2; ++mf) {
        #pragma unroll
        for (int r = 0; r < 4; ++r) {
            int m = wm * 32 + mf * 16 + kg * 4 + r;    // C/D layout: col=lane&15, row=kg*4+reg
            #pragma unroll
            for (int nf = 0; nf < 2; ++nf) {
                float v = fast_tanh(acc[mf][nf][r] + bj[nf]);
                sc[m * 80 + wn * 32 + nf * 16 + lr] = f32_to_fp8(v);
            }
        }
    }
    __syncthreads();
    {
        int row = tid >> 2;                            // 128 rows x 64 B, 16 B per thread
        int off = (tid & 3) * 16;
        uint4 v = *(const uint4*)&sc[row * 80 + off];
        *(uint4*)&table[(size_t)(1 + tok0 + row) * DD + n0 + off] = v;
    }
}

// ---------------- Kernel B: fp8 gather + max over F + dot(w2) + bias + mask ----------------
// R14-verified: 2048 blocks; each wave handles TWO tokens with all 8 gather loads
// interleaved -> 2x memory-level parallelism, half the block count.
__global__ __launch_bounds__(256) void gather_score_kernel(
    const unsigned char* __restrict__ table,
    const int* __restrict__ select_idx,
    const int* __restrict__ word_mask,
    const float* __restrict__ w2,
    const float* __restrict__ b2,
    float* __restrict__ out)
{
    const int tid  = threadIdx.x;
    const int lane = tid & 63;
    const int wv   = tid >> 6;
    const int iA   = blockIdx.x * 8 + wv * 2;     // tokens iA, iA+1
    const int iB   = iA + 1;
    const int half = lane >> 5;
    const int c    = lane & 31;
    const int d0   = c * 8;                        // 8 dims (8 B) per lane

    const int4* spA = (const int4*)(select_idx + (size_t)iA * FF);
    const int4* spB = (const int4*)(select_idx + (size_t)iB * FF);
    int4 qa0 = spA[0], qa1 = spA[1];
    int4 qb0 = spB[0], qb1 = spB[1];
    int rA[4], rB[4];
    rA[0] = half ? qa0.y : qa0.x;  rA[1] = half ? qa0.w : qa0.z;
    rA[2] = half ? qa1.y : qa1.x;  rA[3] = half ? qa1.w : qa1.z;
    rB[0] = half ? qb0.y : qb0.x;  rB[1] = half ? qb0.w : qb0.z;
    rB[2] = half ? qb1.y : qb1.x;  rB[3] = half ? qb1.w : qb1.z;

    uint2 uA[4], uB[4];                            // all 8 gathers in flight together
    #pragma unroll
    for (int it = 0; it < 4; ++it) {
        uA[it] = *(const uint2*)(table + (size_t)rA[it] * DD + d0);
        uB[it] = *(const uint2*)(table + (size_t)rB[it] * DD + d0);
    }

    float mA[8], mB[8];
    #pragma unroll
    for (int j = 0; j < 8; ++j) { mA[j] = -INFINITY; mB[j] = -INFINITY; }

    #pragma unroll
    for (int it = 0; it < 4; ++it) {
        f32x2 a0 = __builtin_amdgcn_cvt_pk_f32_fp8(uA[it].x, false);
        f32x2 a1 = __builtin_amdgcn_cvt_pk_f32_fp8(uA[it].x, true);
        f32x2 a2 = __builtin_amdgcn_cvt_pk_f32_fp8(uA[it].y, false);
        f32x2 a3 = __builtin_amdgcn_cvt_pk_f32_fp8(uA[it].y, true);
        mA[0] = fmaxf(mA[0], a0.x); mA[1] = fmaxf(mA[1], a0.y);
        mA[2] = fmaxf(mA[2], a1.x); mA[3] = fmaxf(mA[3], a1.y);
        mA[4] = fmaxf(mA[4], a2.x); mA[5] = fmaxf(mA[5], a2.y);
        mA[6] = fmaxf(mA[6], a3.x); mA[7] = fmaxf(mA[7], a3.y);
        f32x2 b0 = __builtin_amdgcn_cvt_pk_f32_fp8(uB[it].x, false);
        f32x2 b1v = __builtin_amdgcn_cvt_pk_f32_fp8(uB[it].x, true);
        f32x2 b2v = __builtin_amdgcn_cvt_pk_f32_fp8(uB[it].y, false);
        f32x2 b3 = __builtin_amdgcn_cvt_pk_f32_fp8(uB[it].y, true);
        mB[0] = fmaxf(mB[0], b0.x); mB[1] = fmaxf(mB[1], b0.y);
        mB[2] = fmaxf(mB[2], b1v.x); mB[3] = fmaxf(mB[3], b1v.y);
        mB[4] = fmaxf(mB[4], b2v.x); mB[5] = fmaxf(mB[5], b2v.y);
        mB[6] = fmaxf(mB[6], b3.x); mB[7] = fmaxf(mB[7], b3.y);
    }

    #pragma unroll
    for (int j = 0; j < 8; ++j) {
        mA[j] = fmaxf(mA[j], __shfl_xor(mA[j], 32));
        mB[j] = fmaxf(mB[j], __shfl_xor(mB[j], 32));
    }

    f32x4 wa = *(const f32x4*)&w2[d0];
    f32x4 wb = *(const f32x4*)&w2[d0 + 4];
    float pA = mA[0] * wa.x + mA[1] * wa.y + mA[2] * wa.z + mA[3] * wa.w
             + mA[4] * wb.x + mA[5] * wb.y + mA[6] * wb.z + mA[7] * wb.w;
    float pB = mB[0] * wa.x + mB[1] * wa.y + mB[2] * wa.z + mB[3] * wa.w
             + mB[4] * wb.x + mB[5] * wb.y + mB[6] * wb.z + mB[7] * wb.w;

    #pragma unroll
    for (int off = 16; off; off >>= 1) {
        pA += __shfl_xor(pA, off);
        pB += __shfl_xor(pB, off);
    }

    if (lane == 0) {
        float negA = word_mask[iA] ? 0.f : -10000.f;
        float negB = word_mask[iB] ? 0.f : -10000.f;
        out[iA] = pA + b2[0] + negA;
        out[iB] = pB + b2[0] + negB;
    }
}

extern "C" void kernel_launch(void* const* d_in, const int* in_sizes, int n_in,
                              void* d_out, int out_size, void* d_ws, size_t ws_size,
                              hipStream_t stream) {
    const float* hs    = (const float*)d_in[0];   // [B,S,D] f32
    const int*   sidx  = (const int*)  d_in[1];   // [B,S,F] i32
    const int*   wmask = (const int*)  d_in[2];   // [B,S]   i32
    const float* W1    = (const float*)d_in[3];   // [D,D]   f32
    const float* b1    = (const float*)d_in[4];   // [D]     f32
    const float* w2    = (const float*)d_in[5];   // [D]     f32
    const float* b2    = (const float*)d_in[6];   // [1]     f32
    float* out = (float*)d_out;                   // [B,S]   f32

    unsigned char* table = (unsigned char*)d_ws;  // [1+NTOK, D] fp8 e4m3 (~4.2 MB)

    gemm_tanh_kernel<<<(NTOK / BM) * (DD / BN), 512, 0, stream>>>(hs, W1, b1, table);
    gather_score_kernel<<<NTOK / 8, 256, 0, stream>>>(table, sidx, wmask, w2, b2, out);
}